// Round 8
// baseline (148.622 us; speedup 1.0000x reference)
//
#include <hip/hip_runtime.h>

// NeuralODE: y' = tanh(y@W1+b1)@W2+b2, fixed-step Dopri5, <=48 static iters.
// R9b (identical resubmit; R7 infra failed): R7b structure (4 waves x 2
// col-tiles, 16 rows/block, grid 512 -> 2 blocks/CU, weights as register
// B-frags, row-major [16][SL] staging, b128 frag reads, 2 barriers/eval).
// Three critical-path cuts:
//  (1) staging writes: even/odd lane pair-exchange (shfl_xor 1 = DPP) +
//      v_perm repack -> b32 dword writes, bank-uniform 2/bank (free). Kills
//      the same-dword b16 write serialization (R7b's 6.03e6 conflict cyc).
//  (2) each layer's MFMA chain split 2+2 (two accumulators + add): halves
//      dependent-MFMA latency on the chain.
//  (3) Dopri5 combos as running partials (P3..P6, Ys) folded via post()
//      inside evalF's post-barrier read-latency window; only the final
//      8-fma gen tail remains on the serial path. (Values identical.)

typedef __attribute__((ext_vector_type(8))) short short8;  // 8 bf16 = 4 VGPRs
typedef __attribute__((ext_vector_type(4))) float f32x4;

#define SL 136  // LDS row stride in bf16: 272B = 16B-aligned rows (b128 reads)

__device__ __forceinline__ short f2bf(float f) {
  union { float f; unsigned u; } v; v.f = f;
  return (short)((v.u + 0x8000u) >> 16);  // for weight load only (not hot)
}

__device__ __forceinline__ float fast_tanh(float x) {
  // tanh(x) = 1 - 2/(exp2(c*x)+1), c = 2*log2(e). 5 VALU ops, exact at +-inf.
  float e = __builtin_amdgcn_exp2f(x * 2.88539008177793f);
  float r = __builtin_amdgcn_rcpf(e + 1.0f);
  return __builtin_fmaf(-2.0f, r, 1.0f);
}

__device__ __forceinline__ unsigned cvtpk(float a, float b) {
  unsigned u;
  asm("v_cvt_pk_bf16_f32 %0, %1, %2" : "=v"(u) : "v"(a), "v"(b));
  return u;  // lo = bf16(a), hi = bf16(b)
}

__global__ __launch_bounds__(256, 2)
void node_kernel(const float* __restrict__ tptr, const float* __restrict__ x,
                 const float* __restrict__ W1, const float* __restrict__ b1,
                 const float* __restrict__ W2, const float* __restrict__ b2,
                 float* __restrict__ out) {
  const int tid  = threadIdx.x;
  const int wv   = tid >> 6;      // wave id (0..3); wave owns col-tiles 2wv,2wv+1
  const int lane = tid & 63;
  const int q    = lane >> 4;     // quad within wave
  const int colL = lane & 15;     // col within tile (C layout) / m row (A frag)
  const int par  = colL & 1;      // lane parity for the write-pair exchange
  const int blockRow = blockIdx.x * 16;

  __shared__ short A1[16][SL];   // staged y' (bf16, A-operand layout)
  __shared__ short A2[16][SL];   // staged tanh hidden (bf16)
  __shared__ float sred[256];

  // ---------- weight B-fragments (bf16) + biases into registers ----------
  short8 w1f[2][4], w2f[2][4];
  float b1v[2], b2v[2];
  int ncol[2];
#pragma unroll
  for (int j = 0; j < 2; ++j) {
    const int n = (2 * wv + j) * 16 + colL;
    ncol[j] = n;
    b1v[j] = b1[n]; b2v[j] = b2[n];
#pragma unroll
    for (int kt = 0; kt < 4; ++kt) {
      short8 v1, v2;
#pragma unroll
      for (int i = 0; i < 8; ++i) {
        const int k = kt * 32 + q * 8 + i;
        v1[i] = f2bf(W1[k * 128 + n]);
        v2[i] = f2bf(W2[k * 128 + n]);
      }
      w1f[j][kt] = v1; w2f[j][kt] = v2;
    }
  }

  // ---------- block-wide sum (256 threads) ----------
  auto block_sum = [&](float v) -> float {
    sred[tid] = v;
    __syncthreads();
    if (tid < 64) {
      float s = sred[tid] + sred[tid + 64] + sred[tid + 128] + sred[tid + 192];
#pragma unroll
      for (int o = 32; o > 0; o >>= 1) s += __shfl_down(s, o, 64);
      if (tid == 0) sred[0] = s;
    }
    __syncthreads();
    float r = sred[0];
    __syncthreads();
    return r;
  };

  // ---------- staging addresses ----------
  // Writer: even lane stores rows q*4+{0,1}, odd lane rows q*4+{2,3}, each as
  // one b32 dword covering cols (n&~1, n|1). Bank-uniform 2/bank (free).
  const int rbase = q * 4 + par * 2;
  unsigned* wA1[2]; unsigned* wA2[2];
#pragma unroll
  for (int j = 0; j < 2; ++j) {
    const int nb = ncol[j] & ~1;
    wA1[j] = (unsigned*)&A1[rbase][nb];
    wA2[j] = (unsigned*)&A2[rbase][nb];
  }
  const short* const rd1 = &A1[colL][q * 8];
  const short* const rd2 = &A2[colL][q * 8];

  // pack 4 rows -> 2 dwords (pair-exchange with lane^1) -> 2 b32 writes
  auto stage_pair = [&](unsigned* p, f32x4 v) {
    unsigned A = cvtpk(v[0], v[1]);      // rows 0,1 of own col
    unsigned B = cvtpk(v[2], v[3]);      // rows 2,3 of own col
    unsigned send = par ? A : B;
    unsigned got = (unsigned)__shfl_xor((int)send, 1, 64);
    // even lane: dwords for rows 0,1 = [self, other]; odd: rows 2,3 = [other, self]
    unsigned losrc = par ? got : A;
    unsigned hisrc = par ? B : got;
    p[0] = __builtin_amdgcn_perm(hisrc, losrc, 0x05040100u);               // row rbase
    *(unsigned*)((short*)p + SL) = __builtin_amdgcn_perm(hisrc, losrc, 0x07060302u); // row rbase+1
  };

  // ---------- one f-eval: staging transpose + 2 MFMA layers (split chains) ----
  auto evalF = [&](const f32x4 (&gin)[2], auto&& post, f32x4 (&fout)[2]) {
    stage_pair(wA1[0], gin[0]);
    stage_pair(wA1[1], gin[1]);
    __syncthreads();
    short8 af[4];
#pragma unroll
    for (int kt = 0; kt < 4; ++kt) af[kt] = *(const short8*)(rd1 + kt * 32);
    post();  // partial-combo folds: fills the ds_read latency window
    f32x4 aL0 = {b1v[0], b1v[0], b1v[0], b1v[0]};
    f32x4 aL1 = {b1v[1], b1v[1], b1v[1], b1v[1]};
    f32x4 aH0 = {0.f, 0.f, 0.f, 0.f}, aH1 = {0.f, 0.f, 0.f, 0.f};
    __builtin_amdgcn_s_setprio(1);
    aL0 = __builtin_amdgcn_mfma_f32_16x16x32_bf16(af[0], w1f[0][0], aL0, 0, 0, 0);
    aL1 = __builtin_amdgcn_mfma_f32_16x16x32_bf16(af[0], w1f[1][0], aL1, 0, 0, 0);
    aH0 = __builtin_amdgcn_mfma_f32_16x16x32_bf16(af[2], w1f[0][2], aH0, 0, 0, 0);
    aH1 = __builtin_amdgcn_mfma_f32_16x16x32_bf16(af[2], w1f[1][2], aH1, 0, 0, 0);
    aL0 = __builtin_amdgcn_mfma_f32_16x16x32_bf16(af[1], w1f[0][1], aL0, 0, 0, 0);
    aL1 = __builtin_amdgcn_mfma_f32_16x16x32_bf16(af[1], w1f[1][1], aL1, 0, 0, 0);
    aH0 = __builtin_amdgcn_mfma_f32_16x16x32_bf16(af[3], w1f[0][3], aH0, 0, 0, 0);
    aH1 = __builtin_amdgcn_mfma_f32_16x16x32_bf16(af[3], w1f[1][3], aH1, 0, 0, 0);
    __builtin_amdgcn_s_setprio(0);
    f32x4 th0, th1;
#pragma unroll
    for (int r = 0; r < 4; ++r) {
      th0[r] = fast_tanh(aL0[r] + aH0[r]);
      th1[r] = fast_tanh(aL1[r] + aH1[r]);
    }
    stage_pair(wA2[0], th0);
    stage_pair(wA2[1], th1);
    __syncthreads();
#pragma unroll
    for (int kt = 0; kt < 4; ++kt) af[kt] = *(const short8*)(rd2 + kt * 32);
    f32x4 fL0 = {b2v[0], b2v[0], b2v[0], b2v[0]};
    f32x4 fL1 = {b2v[1], b2v[1], b2v[1], b2v[1]};
    f32x4 fH0 = {0.f, 0.f, 0.f, 0.f}, fH1 = {0.f, 0.f, 0.f, 0.f};
    __builtin_amdgcn_s_setprio(1);
    fL0 = __builtin_amdgcn_mfma_f32_16x16x32_bf16(af[0], w2f[0][0], fL0, 0, 0, 0);
    fL1 = __builtin_amdgcn_mfma_f32_16x16x32_bf16(af[0], w2f[1][0], fL1, 0, 0, 0);
    fH0 = __builtin_amdgcn_mfma_f32_16x16x32_bf16(af[2], w2f[0][2], fH0, 0, 0, 0);
    fH1 = __builtin_amdgcn_mfma_f32_16x16x32_bf16(af[2], w2f[1][2], fH1, 0, 0, 0);
    fL0 = __builtin_amdgcn_mfma_f32_16x16x32_bf16(af[1], w2f[0][1], fL0, 0, 0, 0);
    fL1 = __builtin_amdgcn_mfma_f32_16x16x32_bf16(af[1], w2f[1][1], fL1, 0, 0, 0);
    fH0 = __builtin_amdgcn_mfma_f32_16x16x32_bf16(af[3], w2f[0][3], fH0, 0, 0, 0);
    fH1 = __builtin_amdgcn_mfma_f32_16x16x32_bf16(af[3], w2f[1][3], fH1, 0, 0, 0);
    __builtin_amdgcn_s_setprio(0);
    fout[0] = fL0 + fH0;
    fout[1] = fL1 + fH1;
  };

  // ---------- dt0 via the MFMA evalF on row-0-broadcast state ----------
  float y0j[2], scl[2];
#pragma unroll
  for (int j = 0; j < 2; ++j) {
    y0j[j] = x[ncol[j]];
    scl[j] = 1.4e-8f + fabsf(y0j[j]) * 1.4e-8f;
  }
  f32x4 fb[2], gb[2];
#pragma unroll
  for (int j = 0; j < 2; ++j) gb[j] = (f32x4){y0j[j], y0j[j], y0j[j], y0j[j]};
  evalF(gb, [&] {}, fb);
  float f0j[2] = {fb[0][0], fb[1][0]};
  float t0 = 0.f, t1 = 0.f;
  if (q == 0) {
#pragma unroll
    for (int j = 0; j < 2; ++j) {
      float a = y0j[j] / scl[j]; t0 += a * a;
      float b = f0j[j] / scl[j]; t1 += b * b;
    }
  }
  float d0 = sqrtf(block_sum(t0));
  float d1 = sqrtf(block_sum(t1));
  float h0 = (d0 < 1e-5f || d1 < 1e-5f) ? 1e-6f : 0.01f * d0 / d1;
#pragma unroll
  for (int j = 0; j < 2; ++j) {
    float v = y0j[j] + h0 * f0j[j];
    gb[j] = (f32x4){v, v, v, v};
  }
  evalF(gb, [&] {}, fb);
  float t2 = 0.f;
  if (q == 0) {
#pragma unroll
    for (int j = 0; j < 2; ++j) {
      float a = (fb[j][0] - f0j[j]) / scl[j]; t2 += a * a;
    }
  }
  float d2 = sqrtf(block_sum(t2)) / h0;
  float h1 = (d1 <= 1e-15f && d2 <= 1e-15f) ? fmaxf(1e-6f, h0 * 1e-3f)
                                            : powf(0.01f / (d1 + d2), 0.2f);
  const float dt0v = fminf(100.f * h0, h1);

  // ---------- load state y (C-layout: rows q*4+r, cols ncol[j]) ----------
  f32x4 yr[2];
#pragma unroll
  for (int j = 0; j < 2; ++j)
#pragma unroll
    for (int r = 0; r < 4; ++r)
      yr[j][r] = x[(blockRow + q * 4 + r) * 128 + ncol[j]];

  // ---------- main fixed-step Dopri5 loop (running-partial form) ----------
  const float T = tptr[0] / 10.0f;  // t[0] / TIMESCALE
  float tt = 0.f;
  f32x4 kA[2], kB[2], P3[2], P4[2], P5[2], P6[2], Ys[2], g[2];

#pragma unroll 1
  for (int it = 0; it < 48; ++it) {
    float dt = fminf(fmaxf(T - tt, 0.f), dt0v);
    if (dt <= 0.f) break;  // uniform across threads and blocks; tt only grows
    const float a21 = dt * 0.2f;
    const float a31 = dt * 0.075f,              a32 = dt * 0.225f;
    const float a41 = dt * 0.9777777777777777f, a42 = dt * -3.7333333333333334f,
                a43 = dt * 3.5555555555555554f;
    const float a51 = dt * 2.9525986892242035f, a52 = dt * -11.595793324188385f,
                a53 = dt * 9.822892851699436f,  a54 = dt * -0.2908093278463649f;
    const float a61 = dt * 2.8462752525252526f, a62 = dt * -10.757575757575758f,
                a63 = dt * 8.906422717743473f,  a64 = dt * 0.2784090909090909f,
                a65 = dt * -0.27351165254237287f;
    const float bb1 = dt * 0.0911458333333333f, bb3 = dt * 0.449236298292902f,
                bb4 = dt * 0.6510416666666666f, bb5 = dt * -0.32237617924528303f,
                bb6 = dt * 0.13095238095238096f;

    // k1 = f(yr); init partials (post: off the serial path)
    evalF(yr, [&] {
#pragma unroll
      for (int j = 0; j < 2; ++j) {
        P3[j] = yr[j]; P4[j] = yr[j]; P5[j] = yr[j]; P6[j] = yr[j]; Ys[j] = yr[j];
      }
    }, kA);
#pragma unroll
    for (int j = 0; j < 2; ++j) g[j] = yr[j] + a21 * kA[j];
    // k2; fold k1 into partials
    evalF(g, [&] {
#pragma unroll
      for (int j = 0; j < 2; ++j) {
        P3[j] += a31 * kA[j]; P4[j] += a41 * kA[j]; P5[j] += a51 * kA[j];
        P6[j] += a61 * kA[j]; Ys[j] += bb1 * kA[j];
      }
    }, kB);
#pragma unroll
    for (int j = 0; j < 2; ++j) g[j] = P3[j] + a32 * kB[j];
    // k3; fold k2 (b2 = 0)
    evalF(g, [&] {
#pragma unroll
      for (int j = 0; j < 2; ++j) {
        P4[j] += a42 * kB[j]; P5[j] += a52 * kB[j]; P6[j] += a62 * kB[j];
      }
    }, kA);
#pragma unroll
    for (int j = 0; j < 2; ++j) g[j] = P4[j] + a43 * kA[j];
    // k4; fold k3
    evalF(g, [&] {
#pragma unroll
      for (int j = 0; j < 2; ++j) {
        P5[j] += a53 * kA[j]; P6[j] += a63 * kA[j]; Ys[j] += bb3 * kA[j];
      }
    }, kB);
#pragma unroll
    for (int j = 0; j < 2; ++j) g[j] = P5[j] + a54 * kB[j];
    // k5; fold k4
    evalF(g, [&] {
#pragma unroll
      for (int j = 0; j < 2; ++j) {
        P6[j] += a64 * kB[j]; Ys[j] += bb4 * kB[j];
      }
    }, kA);
#pragma unroll
    for (int j = 0; j < 2; ++j) g[j] = P6[j] + a65 * kA[j];
    // k6; fold k5
    evalF(g, [&] {
#pragma unroll
      for (int j = 0; j < 2; ++j) Ys[j] += bb5 * kA[j];
    }, kB);
#pragma unroll
    for (int j = 0; j < 2; ++j) yr[j] = Ys[j] + bb6 * kB[j];
    tt += dt;
  }

  // ---------- epilogue: out = stack([x, yT]) ----------
  {
    const float4* x4 = (const float4*)(x + blockRow * 128);
    float4* o4 = (float4*)(out + blockRow * 128);
    o4[tid] = x4[tid];              // 16 rows * 128 f32 = 512 float4
    o4[tid + 256] = x4[tid + 256];
    float* oy = out + 8192 * 128;
#pragma unroll
    for (int j = 0; j < 2; ++j)
#pragma unroll
      for (int r = 0; r < 4; ++r)
        oy[(blockRow + q * 4 + r) * 128 + ncol[j]] = yr[j][r];
  }
}

extern "C" void kernel_launch(void* const* d_in, const int* in_sizes, int n_in,
                              void* d_out, int out_size, void* d_ws, size_t ws_size,
                              hipStream_t stream) {
  const float* t  = (const float*)d_in[0];
  const float* x  = (const float*)d_in[1];
  const float* W1 = (const float*)d_in[2];
  const float* b1 = (const float*)d_in[3];
  const float* W2 = (const float*)d_in[4];
  const float* b2 = (const float*)d_in[5];
  float* out = (float*)d_out;
  node_kernel<<<dim3(512), dim3(256), 0, stream>>>(t, x, W1, b1, W2, b2, out);
}

// Round 9
// 142.465 us; speedup vs baseline: 1.0432x; 1.0432x over previous
//
#include <hip/hip_runtime.h>

// NeuralODE: y' = tanh(y@W1+b1)@W2+b2, fixed-step Dopri5, <=48 static iters.
// R10: exact R7b base (4 waves x 2 col-tiles, 16 rows/block, grid 512 ->
// 2 blocks/CU, weights as register B-frags, row-major [16][SL] staging with
// b16-pair writes, b128 frag reads, 2 barriers/eval, exp2-tanh, MFMA dt0)
// + ONE isolated change: each layer's 4-deep dependent MFMA chain split into
// two 2-deep chains (L: kt 0,1 / H: kt 2,3) with a final add. R9's other two
// changes (pair-exchange b32 writes, post() partial folds) are REVERTED --
// R9 proved conflicts are read-path (counter identical under write rework)
// and the fold restructure just added VALU ops the compiler had already
// hidden.

typedef __attribute__((ext_vector_type(8))) short short8;  // 8 bf16 = 4 VGPRs
typedef __attribute__((ext_vector_type(4))) float f32x4;

#define SL 136  // LDS row stride in bf16: 272B = 16B-aligned rows (b128 reads)

__device__ __forceinline__ short f2bf(float f) {
  union { float f; unsigned u; } v; v.f = f;
  return (short)((v.u + 0x8000u) >> 16);  // for weight load only (not hot)
}

__device__ __forceinline__ float fast_tanh(float x) {
  // tanh(x) = 1 - 2/(exp2(c*x)+1), c = 2*log2(e). 5 VALU ops, exact at +-inf.
  float e = __builtin_amdgcn_exp2f(x * 2.88539008177793f);
  float r = __builtin_amdgcn_rcpf(e + 1.0f);
  return __builtin_fmaf(-2.0f, r, 1.0f);
}

// pack 2 f32 -> 2 bf16 in one instr; store lo/hi halves to two LDS addrs
// (compiler folds the hi store to ds_write_b16_d16_hi).
__device__ __forceinline__ void store_bf16_pair(short* p0, short* p1,
                                                float a, float b) {
  unsigned u;
  asm("v_cvt_pk_bf16_f32 %0, %1, %2" : "=v"(u) : "v"(a), "v"(b));
  *p0 = (short)(u & 0xffffu);
  *p1 = (short)(u >> 16);
}

__global__ __launch_bounds__(256, 2)
void node_kernel(const float* __restrict__ tptr, const float* __restrict__ x,
                 const float* __restrict__ W1, const float* __restrict__ b1,
                 const float* __restrict__ W2, const float* __restrict__ b2,
                 float* __restrict__ out) {
  const int tid  = threadIdx.x;
  const int wv   = tid >> 6;      // wave id (0..3); wave owns col-tiles 2wv,2wv+1
  const int lane = tid & 63;
  const int q    = lane >> 4;     // quad within wave
  const int colL = lane & 15;     // col within tile (C layout) / m row (A frag)
  const int blockRow = blockIdx.x * 16;

  __shared__ short A1[16][SL];   // staged y' (bf16, A-operand layout)
  __shared__ short A2[16][SL];   // staged tanh hidden (bf16)
  __shared__ float sred[256];

  // ---------- weight B-fragments (bf16) + biases into registers ----------
  // B-frag 16x16x32: lane holds B[k = kt*32 + quad*8 + i][n], i=0..7.
  short8 w1f[2][4], w2f[2][4];
  float b1v[2], b2v[2];
  int ncol[2];
#pragma unroll
  for (int j = 0; j < 2; ++j) {
    const int n = (2 * wv + j) * 16 + colL;
    ncol[j] = n;
    b1v[j] = b1[n]; b2v[j] = b2[n];
#pragma unroll
    for (int kt = 0; kt < 4; ++kt) {
      short8 v1, v2;
#pragma unroll
      for (int i = 0; i < 8; ++i) {
        const int k = kt * 32 + q * 8 + i;
        v1[i] = f2bf(W1[k * 128 + n]);
        v2[i] = f2bf(W2[k * 128 + n]);
      }
      w1f[j][kt] = v1; w2f[j][kt] = v2;
    }
  }

  // ---------- block-wide sum (256 threads) ----------
  auto block_sum = [&](float v) -> float {
    sred[tid] = v;
    __syncthreads();
    if (tid < 64) {
      float s = sred[tid] + sred[tid + 64] + sred[tid + 128] + sred[tid + 192];
#pragma unroll
      for (int o = 32; o > 0; o >>= 1) s += __shfl_down(s, o, 64);
      if (tid == 0) sred[0] = s;
    }
    __syncthreads();
    float r = sred[0];
    __syncthreads();
    return r;
  };

  // hoisted LDS addresses (constant immediate offsets thereafter)
  short* const wr1 = &A1[q * 4][0];
  short* const wr2 = &A2[q * 4][0];
  const short* const rd1 = &A1[colL][q * 8];
  const short* const rd2 = &A2[colL][q * 8];

  // ---------- one f-eval: LDS round-trip transpose + 2 MFMA layers ----------
  // MFMA per layer: two independent 2-deep chains (L: kt0,1 / H: kt2,3),
  // interleaved across both col-tiles, summed at the end.
  auto evalF = [&](auto&& gen, f32x4 (&fout)[2]) {
#pragma unroll
    for (int j = 0; j < 2; ++j) {
      f32x4 v = gen(j);
      store_bf16_pair(&wr1[0 * SL + ncol[j]], &wr1[1 * SL + ncol[j]], v[0], v[1]);
      store_bf16_pair(&wr1[2 * SL + ncol[j]], &wr1[3 * SL + ncol[j]], v[2], v[3]);
    }
    __syncthreads();
    short8 af[4];
#pragma unroll
    for (int kt = 0; kt < 4; ++kt) af[kt] = *(const short8*)(rd1 + kt * 32);
    f32x4 aL0 = {b1v[0], b1v[0], b1v[0], b1v[0]};
    f32x4 aL1 = {b1v[1], b1v[1], b1v[1], b1v[1]};
    f32x4 aH0 = {0.f, 0.f, 0.f, 0.f}, aH1 = {0.f, 0.f, 0.f, 0.f};
    __builtin_amdgcn_s_setprio(1);
    aL0 = __builtin_amdgcn_mfma_f32_16x16x32_bf16(af[0], w1f[0][0], aL0, 0, 0, 0);
    aL1 = __builtin_amdgcn_mfma_f32_16x16x32_bf16(af[0], w1f[1][0], aL1, 0, 0, 0);
    aH0 = __builtin_amdgcn_mfma_f32_16x16x32_bf16(af[2], w1f[0][2], aH0, 0, 0, 0);
    aH1 = __builtin_amdgcn_mfma_f32_16x16x32_bf16(af[2], w1f[1][2], aH1, 0, 0, 0);
    aL0 = __builtin_amdgcn_mfma_f32_16x16x32_bf16(af[1], w1f[0][1], aL0, 0, 0, 0);
    aL1 = __builtin_amdgcn_mfma_f32_16x16x32_bf16(af[1], w1f[1][1], aL1, 0, 0, 0);
    aH0 = __builtin_amdgcn_mfma_f32_16x16x32_bf16(af[3], w1f[0][3], aH0, 0, 0, 0);
    aH1 = __builtin_amdgcn_mfma_f32_16x16x32_bf16(af[3], w1f[1][3], aH1, 0, 0, 0);
    __builtin_amdgcn_s_setprio(0);
    {
      float h0a = fast_tanh(aL0[0] + aH0[0]), h1a = fast_tanh(aL0[1] + aH0[1]);
      float h2a = fast_tanh(aL0[2] + aH0[2]), h3a = fast_tanh(aL0[3] + aH0[3]);
      store_bf16_pair(&wr2[0 * SL + ncol[0]], &wr2[1 * SL + ncol[0]], h0a, h1a);
      store_bf16_pair(&wr2[2 * SL + ncol[0]], &wr2[3 * SL + ncol[0]], h2a, h3a);
      float h0b = fast_tanh(aL1[0] + aH1[0]), h1b = fast_tanh(aL1[1] + aH1[1]);
      float h2b = fast_tanh(aL1[2] + aH1[2]), h3b = fast_tanh(aL1[3] + aH1[3]);
      store_bf16_pair(&wr2[0 * SL + ncol[1]], &wr2[1 * SL + ncol[1]], h0b, h1b);
      store_bf16_pair(&wr2[2 * SL + ncol[1]], &wr2[3 * SL + ncol[1]], h2b, h3b);
    }
    __syncthreads();
#pragma unroll
    for (int kt = 0; kt < 4; ++kt) af[kt] = *(const short8*)(rd2 + kt * 32);
    f32x4 fL0 = {b2v[0], b2v[0], b2v[0], b2v[0]};
    f32x4 fL1 = {b2v[1], b2v[1], b2v[1], b2v[1]};
    f32x4 fH0 = {0.f, 0.f, 0.f, 0.f}, fH1 = {0.f, 0.f, 0.f, 0.f};
    __builtin_amdgcn_s_setprio(1);
    fL0 = __builtin_amdgcn_mfma_f32_16x16x32_bf16(af[0], w2f[0][0], fL0, 0, 0, 0);
    fL1 = __builtin_amdgcn_mfma_f32_16x16x32_bf16(af[0], w2f[1][0], fL1, 0, 0, 0);
    fH0 = __builtin_amdgcn_mfma_f32_16x16x32_bf16(af[2], w2f[0][2], fH0, 0, 0, 0);
    fH1 = __builtin_amdgcn_mfma_f32_16x16x32_bf16(af[2], w2f[1][2], fH1, 0, 0, 0);
    fL0 = __builtin_amdgcn_mfma_f32_16x16x32_bf16(af[1], w2f[0][1], fL0, 0, 0, 0);
    fL1 = __builtin_amdgcn_mfma_f32_16x16x32_bf16(af[1], w2f[1][1], fL1, 0, 0, 0);
    fH0 = __builtin_amdgcn_mfma_f32_16x16x32_bf16(af[3], w2f[0][3], fH0, 0, 0, 0);
    fH1 = __builtin_amdgcn_mfma_f32_16x16x32_bf16(af[3], w2f[1][3], fH1, 0, 0, 0);
    __builtin_amdgcn_s_setprio(0);
    fout[0] = fL0 + fH0;
    fout[1] = fL1 + fH1;
  };

  // ---------- dt0 via the MFMA evalF on row-0-broadcast state ----------
  float y0j[2], scl[2];
#pragma unroll
  for (int j = 0; j < 2; ++j) {
    y0j[j] = x[ncol[j]];
    scl[j] = 1.4e-8f + fabsf(y0j[j]) * 1.4e-8f;
  }
  f32x4 fb[2];
  evalF([&](int j) { float v = y0j[j]; return (f32x4){v, v, v, v}; }, fb);
  float f0j[2] = {fb[0][0], fb[1][0]};
  float t0 = 0.f, t1 = 0.f;
  if (q == 0) {
#pragma unroll
    for (int j = 0; j < 2; ++j) {
      float a = y0j[j] / scl[j]; t0 += a * a;
      float b = f0j[j] / scl[j]; t1 += b * b;
    }
  }
  float d0 = sqrtf(block_sum(t0));
  float d1 = sqrtf(block_sum(t1));
  float h0 = (d0 < 1e-5f || d1 < 1e-5f) ? 1e-6f : 0.01f * d0 / d1;
  evalF([&](int j) { float v = y0j[j] + h0 * f0j[j]; return (f32x4){v, v, v, v}; }, fb);
  float t2 = 0.f;
  if (q == 0) {
#pragma unroll
    for (int j = 0; j < 2; ++j) {
      float a = (fb[j][0] - f0j[j]) / scl[j]; t2 += a * a;
    }
  }
  float d2 = sqrtf(block_sum(t2)) / h0;
  float h1 = (d1 <= 1e-15f && d2 <= 1e-15f) ? fmaxf(1e-6f, h0 * 1e-3f)
                                            : powf(0.01f / (d1 + d2), 0.2f);
  const float dt0v = fminf(100.f * h0, h1);

  // ---------- load state y (C-layout: rows q*4+r, cols ncol[j]) ----------
  f32x4 yr[2];
#pragma unroll
  for (int j = 0; j < 2; ++j)
#pragma unroll
    for (int r = 0; r < 4; ++r)
      yr[j][r] = x[(blockRow + q * 4 + r) * 128 + ncol[j]];

  // ---------- main fixed-step Dopri5 loop ----------
  const float T = tptr[0] / 10.0f;  // t[0] / TIMESCALE
  float tt = 0.f;
  f32x4 k1[2], k2[2], k3[2], k4[2], k5[2], k6[2];

#pragma unroll 1
  for (int it = 0; it < 48; ++it) {
    float dt = fminf(fmaxf(T - tt, 0.f), dt0v);
    if (dt <= 0.f) break;  // uniform across threads and blocks; tt only grows
    evalF([&](int j) { return yr[j]; }, k1);
    {
      const float c1 = dt * 0.2f;
      evalF([&](int j) { return yr[j] + c1 * k1[j]; }, k2);
    }
    {
      const float c1 = dt * 0.075f, c2 = dt * 0.225f;
      evalF([&](int j) { return yr[j] + c1 * k1[j] + c2 * k2[j]; }, k3);
    }
    {
      const float c1 = dt * 0.9777777777777777f, c2 = dt * -3.7333333333333334f,
                  c3 = dt * 3.5555555555555554f;
      evalF([&](int j) { return yr[j] + c1 * k1[j] + c2 * k2[j] + c3 * k3[j]; }, k4);
    }
    {
      const float c1 = dt * 2.9525986892242035f, c2 = dt * -11.595793324188385f,
                  c3 = dt * 9.822892851699436f, c4 = dt * -0.2908093278463649f;
      evalF([&](int j) {
        return yr[j] + c1 * k1[j] + c2 * k2[j] + c3 * k3[j] + c4 * k4[j];
      }, k5);
    }
    {
      const float c1 = dt * 2.8462752525252526f, c2 = dt * -10.757575757575758f,
                  c3 = dt * 8.906422717743473f, c4 = dt * 0.2784090909090909f,
                  c5 = dt * -0.27351165254237287f;
      evalF([&](int j) {
        return yr[j] + c1 * k1[j] + c2 * k2[j] + c3 * k3[j] + c4 * k4[j]
                     + c5 * k5[j];
      }, k6);
    }
    {
      const float c1 = dt * 0.0911458333333333f, c3 = dt * 0.449236298292902f,
                  c4 = dt * 0.6510416666666666f, c5 = dt * -0.32237617924528303f,
                  c6 = dt * 0.13095238095238096f;
#pragma unroll
      for (int j = 0; j < 2; ++j)
        yr[j] = yr[j] + c1 * k1[j] + c3 * k3[j] + c4 * k4[j] + c5 * k5[j]
                      + c6 * k6[j];
    }
    tt += dt;
  }

  // ---------- epilogue: out = stack([x, yT]) ----------
  {
    const float4* x4 = (const float4*)(x + blockRow * 128);
    float4* o4 = (float4*)(out + blockRow * 128);
    o4[tid] = x4[tid];              // 16 rows * 128 f32 = 512 float4
    o4[tid + 256] = x4[tid + 256];
    float* oy = out + 8192 * 128;
#pragma unroll
    for (int j = 0; j < 2; ++j)
#pragma unroll
      for (int r = 0; r < 4; ++r)
        oy[(blockRow + q * 4 + r) * 128 + ncol[j]] = yr[j][r];
  }
}

extern "C" void kernel_launch(void* const* d_in, const int* in_sizes, int n_in,
                              void* d_out, int out_size, void* d_ws, size_t ws_size,
                              hipStream_t stream) {
  const float* t  = (const float*)d_in[0];
  const float* x  = (const float*)d_in[1];
  const float* W1 = (const float*)d_in[2];
  const float* b1 = (const float*)d_in[3];
  const float* W2 = (const float*)d_in[4];
  const float* b2 = (const float*)d_in[5];
  float* out = (float*)d_out;
  node_kernel<<<dim3(512), dim3(256), 0, stream>>>(t, x, W1, b1, W2, b2, out);
}